// Round 2
// baseline (1537.499 us; speedup 1.0000x reference)
//
#include <hip/hip_runtime.h>

// Problem constants (fixed by reference)
#define NN 100000
#define NE 1600000
#define NG 2000
#define NFE 32000

#define SCAN_CHUNK 2048
#define SCAN_T 256
#define SCAN_V 8

// ---------------- histogram / degree ----------------
__global__ void k_count(const int* __restrict__ ids, int* __restrict__ counts, int n) {
    int i = blockIdx.x * blockDim.x + threadIdx.x;
    if (i < n) atomicAdd(&counts[ids[i]], 1);
}

__global__ void k_dinv(const int* __restrict__ counts, float* __restrict__ dinv, int n) {
    int i = blockIdx.x * blockDim.x + threadIdx.x;
    if (i < n) dinv[i] = rsqrtf((float)counts[i] + 1.0f);
}

// ---------------- 3-kernel exclusive scan ----------------
__global__ void k_scan_partial(const int* __restrict__ in, int* __restrict__ part, int n) {
    __shared__ int red[SCAN_T];
    int t = threadIdx.x;
    int base = blockIdx.x * SCAN_CHUNK + t * SCAN_V;
    int s = 0;
#pragma unroll
    for (int j = 0; j < SCAN_V; j++) {
        int idx = base + j;
        if (idx < n) s += in[idx];
    }
    red[t] = s;
    __syncthreads();
    for (int st = SCAN_T / 2; st > 0; st >>= 1) {
        if (t < st) red[t] += red[t + st];
        __syncthreads();
    }
    if (t == 0) part[blockIdx.x] = red[0];
}

// single block: exclusive scan of part[0..nb) in place (nb <= 256)
__global__ void k_scan_small(int* __restrict__ part, int nb) {
    __shared__ int sh[SCAN_T];
    int t = threadIdx.x;
    int v = (t < nb) ? part[t] : 0;
    sh[t] = v;
    __syncthreads();
    for (int st = 1; st < SCAN_T; st <<= 1) {
        int x = (t >= st) ? sh[t - st] : 0;
        __syncthreads();
        sh[t] += x;
        __syncthreads();
    }
    if (t < nb) part[t] = sh[t] - v;  // exclusive
}

__global__ void k_scan_apply(const int* __restrict__ in, const int* __restrict__ part,
                             int* __restrict__ out, int* __restrict__ out2, int n) {
    __shared__ int red[SCAN_T];
    int t = threadIdx.x;
    int base = blockIdx.x * SCAN_CHUNK + t * SCAN_V;
    int vals[SCAN_V];
    int s = 0;
#pragma unroll
    for (int j = 0; j < SCAN_V; j++) {
        int idx = base + j;
        vals[j] = (idx < n) ? in[idx] : 0;
        s += vals[j];
    }
    red[t] = s;
    __syncthreads();
    for (int st = 1; st < SCAN_T; st <<= 1) {
        int x = (t >= st) ? red[t - st] : 0;
        __syncthreads();
        red[t] += x;
        __syncthreads();
    }
    int texcl = red[t] - s;
    int run = part[blockIdx.x] + texcl;
#pragma unroll
    for (int j = 0; j < SCAN_V; j++) {
        int idx = base + j;
        if (idx < n) {
            out[idx] = run;
            if (out2) out2[idx] = run;
            run += vals[j];
            if (idx == n - 1) {  // write total at position n
                out[n] = run;
                if (out2) out2[n] = run;
            }
        }
    }
}

// ---------------- CSR fill ----------------
__global__ void k_fill(const int* __restrict__ src, const int* __restrict__ dst,
                       const float* __restrict__ dinv, int* __restrict__ cursor,
                       int* __restrict__ csr_src, float* __restrict__ csr_w, int n) {
    int i = blockIdx.x * blockDim.x + threadIdx.x;
    if (i < n) {
        int s = src[i], d = dst[i];
        int pos = atomicAdd(&cursor[d], 1);
        csr_src[pos] = s;
        csr_w[pos] = dinv[s] * dinv[d];
    }
}

// ---------------- propagation: out[n] = dinv[n]^2 * x[n] + sum_e w_e * x[src_e] ----------------
// one wave per node; lanes cover channels via float2; C in {128,156,184}
template <int C>
__global__ void k_prop_t(const float* __restrict__ x, const int* __restrict__ off,
                         const int* __restrict__ srcs, const float* __restrict__ w,
                         const float* __restrict__ dinv, const float* __restrict__ bias,
                         float* __restrict__ out, int n, int relu) {
    constexpr int NCH = C / 128;      // full 128-float chunks (as 64 float2 lanes)
    constexpr int REM = C % 128;      // remainder floats (even for all our C)
    constexpr int NACC = NCH + (REM ? 1 : 0);
    int node = (int)((blockIdx.x * (size_t)blockDim.x + threadIdx.x) >> 6);
    int lane = threadIdx.x & 63;
    if (node >= n) return;
    float dv = dinv[node];
    float sw = dv * dv;
    const float2* xr = (const float2*)(x + (size_t)node * C);
    bool remAct = (REM != 0) && (lane * 2 < REM);
    float2 acc[NACC];
#pragma unroll
    for (int j = 0; j < NCH; j++) {
        float2 v = xr[lane + 64 * j];
        acc[j].x = sw * v.x; acc[j].y = sw * v.y;
    }
    if (REM) {
        acc[NCH].x = 0.f; acc[NCH].y = 0.f;
        if (remAct) {
            float2 v = xr[NCH * 64 + lane];
            acc[NCH].x = sw * v.x; acc[NCH].y = sw * v.y;
        }
    }
    int e0 = off[node], e1 = off[node + 1];
    for (int e = e0; e < e1; e++) {
        int s = srcs[e];
        float ww = w[e];
        const float2* xs = (const float2*)(x + (size_t)s * C);
#pragma unroll
        for (int j = 0; j < NCH; j++) {
            float2 v = xs[lane + 64 * j];
            acc[j].x += ww * v.x; acc[j].y += ww * v.y;
        }
        if (REM && remAct) {
            float2 v = xs[NCH * 64 + lane];
            acc[NCH].x += ww * v.x; acc[NCH].y += ww * v.y;
        }
    }
    float2* orow = (float2*)(out + (size_t)node * C);
#pragma unroll
    for (int j = 0; j < NCH; j++) {
        int idx = lane + 64 * j;
        float2 v = acc[j];
        if (bias) { v.x += bias[idx * 2]; v.y += bias[idx * 2 + 1]; }
        if (relu) { v.x = fmaxf(v.x, 0.f); v.y = fmaxf(v.y, 0.f); }
        orow[idx] = v;
    }
    if (REM && remAct) {
        int idx = NCH * 64 + lane;
        float2 v = acc[NCH];
        if (bias) { v.x += bias[idx * 2]; v.y += bias[idx * 2 + 1]; }
        if (relu) { v.x = fmaxf(v.x, 0.f); v.y = fmaxf(v.y, 0.f); }
        orow[idx] = v;
    }
}

// ---------------- big GEMM: out[M,O] = A[M,K] @ W[O,K]^T (+bias, relu) ----------------
// 128x64 tile, 8x4 per thread, BK=16, float4 staging. K constexpr, K%4==0, O%4==0.
#define GBM 128
#define GBN 64
#define GBK 16
template <int K>
__global__ __launch_bounds__(256) void k_gemm_big(const float* __restrict__ A, const float* __restrict__ W,
                                                  const float* __restrict__ bias, float* __restrict__ out,
                                                  int M, int O, int relu) {
    __shared__ float As[GBK][GBM + 4];
    __shared__ float Bs[GBK][GBN + 4];
    int tid = threadIdx.x;
    int tx = tid & 15;        // 16 col groups of 4
    int ty = tid >> 4;        // 16 row groups of 8
    int row0 = blockIdx.x * GBM, col0 = blockIdx.y * GBN;
    float acc[8][4] = {};
    for (int k0 = 0; k0 < K; k0 += GBK) {
        // stage A: 128 rows x 16 k = 512 float4
#pragma unroll
        for (int l = 0; l < 2; l++) {
            int idx = tid + l * 256;
            int m = idx >> 2, kq = idx & 3;
            int r = row0 + m, k = k0 + kq * 4;
            float4 v = {0.f, 0.f, 0.f, 0.f};
            if (r < M && k < K) v = *(const float4*)(A + (size_t)r * K + k);
            As[kq * 4 + 0][m] = v.x;
            As[kq * 4 + 1][m] = v.y;
            As[kq * 4 + 2][m] = v.z;
            As[kq * 4 + 3][m] = v.w;
        }
        // stage B: 64 rows x 16 k = 256 float4
        {
            int m = tid >> 2, kq = tid & 3;
            int c = col0 + m, k = k0 + kq * 4;
            float4 v = {0.f, 0.f, 0.f, 0.f};
            if (c < O && k < K) v = *(const float4*)(W + (size_t)c * K + k);
            Bs[kq * 4 + 0][m] = v.x;
            Bs[kq * 4 + 1][m] = v.y;
            Bs[kq * 4 + 2][m] = v.z;
            Bs[kq * 4 + 3][m] = v.w;
        }
        __syncthreads();
#pragma unroll
        for (int kk = 0; kk < GBK; kk++) {
            float a[8], b[4];
#pragma unroll
            for (int i = 0; i < 8; i++) a[i] = As[kk][ty * 8 + i];
#pragma unroll
            for (int j = 0; j < 4; j++) b[j] = Bs[kk][tx * 4 + j];
#pragma unroll
            for (int i = 0; i < 8; i++)
#pragma unroll
                for (int j = 0; j < 4; j++) acc[i][j] += a[i] * b[j];
        }
        __syncthreads();
    }
    int c = col0 + tx * 4;
    if (c < O) {  // O%4==0 so the float4 is all-or-nothing
        float4 bv = {0.f, 0.f, 0.f, 0.f};
        if (bias) bv = *(const float4*)(bias + c);
#pragma unroll
        for (int i = 0; i < 8; i++) {
            int r = row0 + ty * 8 + i;
            if (r >= M) continue;
            float4 v;
            v.x = acc[i][0] + bv.x;
            v.y = acc[i][1] + bv.y;
            v.z = acc[i][2] + bv.z;
            v.w = acc[i][3] + bv.w;
            if (relu) {
                v.x = fmaxf(v.x, 0.f); v.y = fmaxf(v.y, 0.f);
                v.z = fmaxf(v.z, 0.f); v.w = fmaxf(v.w, 0.f);
            }
            *(float4*)(out + (size_t)r * O + c) = v;
        }
    }
}

// ---------------- small GEMM: out[M,O] = A[M,K] @ W[O,K]^T (+bias, relu) ----------------
#define BM 64
#define BN 64
#define BK 16
__global__ __launch_bounds__(256) void k_gemm(const float* __restrict__ A, const float* __restrict__ W,
                                              const float* __restrict__ bias, float* __restrict__ out,
                                              int M, int K, int O, int relu) {
    __shared__ float As[BK][BM + 4];
    __shared__ float Bs[BK][BN + 4];
    int tid = threadIdx.x;
    int tx = tid % 16, ty = tid / 16;
    int row0 = blockIdx.x * BM, col0 = blockIdx.y * BN;
    float acc[4][4] = {};
    for (int k0 = 0; k0 < K; k0 += BK) {
        for (int t = tid; t < BM * BK; t += 256) {
            int m = t / BK, kk = t % BK;
            float v = 0.f;
            int r = row0 + m, k = k0 + kk;
            if (r < M && k < K) v = A[(size_t)r * K + k];
            As[kk][m] = v;
        }
        for (int t = tid; t < BN * BK; t += 256) {
            int o = t / BK, kk = t % BK;
            float v = 0.f;
            int c = col0 + o, k = k0 + kk;
            if (c < O && k < K) v = W[(size_t)c * K + k];
            Bs[kk][o] = v;
        }
        __syncthreads();
#pragma unroll
        for (int kk = 0; kk < BK; kk++) {
            float a[4], b[4];
#pragma unroll
            for (int i = 0; i < 4; i++) a[i] = As[kk][ty * 4 + i];
#pragma unroll
            for (int j = 0; j < 4; j++) b[j] = Bs[kk][tx * 4 + j];
#pragma unroll
            for (int i = 0; i < 4; i++)
#pragma unroll
                for (int j = 0; j < 4; j++) acc[i][j] += a[i] * b[j];
        }
        __syncthreads();
    }
#pragma unroll
    for (int i = 0; i < 4; i++) {
        int r = row0 + ty * 4 + i;
        if (r >= M) continue;
#pragma unroll
        for (int j = 0; j < 4; j++) {
            int c = col0 + tx * 4 + j;
            if (c >= O) continue;
            float v = acc[i][j] + (bias ? bias[c] : 0.f);
            if (relu) v = fmaxf(v, 0.f);
            out[(size_t)r * O + c] = v;
        }
    }
}

// ---------------- mean pool (batch sorted -> contiguous segments) ----------------
__global__ void k_pool(const float* __restrict__ x, const int* __restrict__ goff,
                       float* __restrict__ out, int C) {
    int g = blockIdx.x;
    int c = threadIdx.x;
    if (c >= C) return;
    int r0 = goff[g], r1 = goff[g + 1];
    float s = 0.f;
    for (int r = r0; r < r1; r++) s += x[(size_t)r * C + c];
    float cnt = (float)(r1 - r0);
    out[(size_t)g * C + c] = s / fmaxf(cnt, 1.0f);
}

// ---------------- batchnorm over rows (per column stats), optional residual add ----------------
__global__ void k_bn(const float* __restrict__ x, const float* __restrict__ gamma,
                     const float* __restrict__ beta, const float* __restrict__ residual,
                     float* __restrict__ out, int G_, int C) {
    int c = blockIdx.x;
    __shared__ float red[256];
    int t = threadIdx.x;
    float s = 0.f;
    for (int r = t; r < G_; r += 256) s += x[(size_t)r * C + c];
    red[t] = s;
    __syncthreads();
    for (int st = 128; st > 0; st >>= 1) {
        if (t < st) red[t] += red[t + st];
        __syncthreads();
    }
    float mean = red[0] / (float)G_;
    __syncthreads();
    float v = 0.f;
    for (int r = t; r < G_; r += 256) {
        float d = x[(size_t)r * C + c] - mean;
        v += d * d;
    }
    red[t] = v;
    __syncthreads();
    for (int st = 128; st > 0; st >>= 1) {
        if (t < st) red[t] += red[t + st];
        __syncthreads();
    }
    float var = red[0] / (float)G_;
    float scale = rsqrtf(var + 1e-5f) * gamma[c];
    float shift = beta[c];
    for (int r = t; r < G_; r += 256) {
        float o = (x[(size_t)r * C + c] - mean) * scale + shift;
        if (residual) o += residual[(size_t)r * C + c];
        out[(size_t)r * C + c] = o;
    }
}

extern "C" void kernel_launch(void* const* d_in, const int* in_sizes, int n_in,
                              void* d_out, int out_size, void* d_ws, size_t ws_size,
                              hipStream_t stream) {
    (void)in_sizes; (void)n_in; (void)out_size; (void)ws_size;
    const float* x      = (const float*)d_in[0];
    const int*   ei     = (const int*)d_in[1];   // [2, NE]
    const int*   batch  = (const int*)d_in[2];
    const int*   fei    = (const int*)d_in[3];   // [2, NFE]
    const float* W_gcn  = (const float*)d_in[4];  const float* b_gcn  = (const float*)d_in[5];
    const float* W_gcnx = (const float*)d_in[6];  const float* b_gcnx = (const float*)d_in[7];
    const float* W_gcny = (const float*)d_in[8];  const float* b_gcny = (const float*)d_in[9];
    const float* W_g1   = (const float*)d_in[10]; const float* b_g1   = (const float*)d_in[11];
    const float* W_g2   = (const float*)d_in[12]; const float* b_g2   = (const float*)d_in[13];
    const float* W_g3   = (const float*)d_in[14]; const float* b_g3   = (const float*)d_in[15];
    const float* gamma0 = (const float*)d_in[16]; const float* beta0  = (const float*)d_in[17];
    const float* gamma1 = (const float*)d_in[18]; const float* beta1  = (const float*)d_in[19];
    const float* gamma2 = (const float*)d_in[20]; const float* beta2  = (const float*)d_in[21];
    const float* gamma3 = (const float*)d_in[22]; const float* beta3  = (const float*)d_in[23];
    const float* Wc1    = (const float*)d_in[24]; const float* bc1    = (const float*)d_in[25];
    const float* Wc2    = (const float*)d_in[26]; const float* bc2    = (const float*)d_in[27];
    float* outp = (float*)d_out;

    char* ws = (char*)d_ws;
    size_t off = 0;
    auto alloc = [&](size_t bytes) -> char* {
        char* p = ws + off;
        off = (off + bytes + 255) & ~(size_t)255;
        return p;
    };

    int*   counts_f = (int*)alloc((size_t)NN * 4);
    int*   off_f    = (int*)alloc((size_t)(NN + 1) * 4);
    int*   cur_f    = (int*)alloc((size_t)(NN + 1) * 4);
    int*   csrc_f   = (int*)alloc((size_t)NE * 4);
    float* csw_f    = (float*)alloc((size_t)NE * 4);
    float* dinv_f   = (float*)alloc((size_t)NN * 4);

    int*   counts_g = (int*)alloc((size_t)NG * 4);
    int*   off_g    = (int*)alloc((size_t)(NG + 1) * 4);
    int*   cur_g    = (int*)alloc((size_t)(NG + 1) * 4);
    int*   csrc_g   = (int*)alloc((size_t)NFE * 4);
    float* csw_g    = (float*)alloc((size_t)NFE * 4);
    float* dinv_g   = (float*)alloc((size_t)NG * 4);

    int*   gcnt = (int*)alloc((size_t)NG * 4);
    int*   goff = (int*)alloc((size_t)(NG + 1) * 4);
    int*   part = (int*)alloc(1024 * 4);

    float* bufA   = (float*)alloc((size_t)NN * 156 * 4);
    float* bufB   = (float*)alloc((size_t)NN * 184 * 4);
    float* pooled = (float*)alloc((size_t)NG * 184 * 4);
    float* xn1    = (float*)alloc((size_t)NG * 128 * 4);
    float* xn2    = (float*)alloc((size_t)NG * 156 * 4);
    float* xn3    = (float*)alloc((size_t)NG * 184 * 4);
    float* ctA    = (float*)alloc((size_t)NG * 212 * 4);
    float* ctB    = (float*)alloc((size_t)NG * 212 * 4);

    auto cdiv = [](int a, int b) { return (a + b - 1) / b; };

    hipMemsetAsync(counts_f, 0, (size_t)NN * 4, stream);
    hipMemsetAsync(counts_g, 0, (size_t)NG * 4, stream);
    hipMemsetAsync(gcnt,     0, (size_t)NG * 4, stream);

    // ---- fine graph CSR ----
    k_count<<<cdiv(NE, 256), 256, 0, stream>>>(ei + NE, counts_f, NE);
    k_dinv<<<cdiv(NN, 256), 256, 0, stream>>>(counts_f, dinv_f, NN);
    int nbN = cdiv(NN, SCAN_CHUNK);
    k_scan_partial<<<nbN, SCAN_T, 0, stream>>>(counts_f, part, NN);
    k_scan_small<<<1, SCAN_T, 0, stream>>>(part, nbN);
    k_scan_apply<<<nbN, SCAN_T, 0, stream>>>(counts_f, part, off_f, cur_f, NN);
    k_fill<<<cdiv(NE, 256), 256, 0, stream>>>(ei, ei + NE, dinv_f, cur_f, csrc_f, csw_f, NE);

    // ---- full (coarse) graph CSR ----
    k_count<<<cdiv(NFE, 256), 256, 0, stream>>>(fei + NFE, counts_g, NFE);
    k_dinv<<<cdiv(NG, 256), 256, 0, stream>>>(counts_g, dinv_g, NG);
    int nbG = cdiv(NG, SCAN_CHUNK);
    k_scan_partial<<<nbG, SCAN_T, 0, stream>>>(counts_g, part, NG);
    k_scan_small<<<1, SCAN_T, 0, stream>>>(part, nbG);
    k_scan_apply<<<nbG, SCAN_T, 0, stream>>>(counts_g, part, off_g, cur_g, NG);
    k_fill<<<cdiv(NFE, 256), 256, 0, stream>>>(fei, fei + NFE, dinv_g, cur_g, csrc_g, csw_g, NFE);

    // ---- pooling offsets from sorted batch ----
    k_count<<<cdiv(NN, 256), 256, 0, stream>>>(batch, gcnt, NN);
    k_scan_partial<<<nbG, SCAN_T, 0, stream>>>(gcnt, part, NG);
    k_scan_small<<<1, SCAN_T, 0, stream>>>(part, nbG);
    k_scan_apply<<<nbG, SCAN_T, 0, stream>>>(gcnt, part, goff, nullptr, NG);

    // ==== fine branch ====
    // layer 1: t = x @ W_gcn^T (200->128), then h1 = relu(prop(t) + b_gcn)
    k_gemm_big<200><<<dim3(cdiv(NN, GBM), cdiv(128, GBN)), 256, 0, stream>>>(x, W_gcn, nullptr, bufA, NN, 128, 0);
    k_prop_t<128><<<cdiv(NN, 4), 256, 0, stream>>>(bufA, off_f, csrc_f, csw_f, dinv_f, b_gcn, bufB, NN, 1);
    k_pool<<<NG, 256, 0, stream>>>(bufB, goff, pooled, 128);
    k_bn<<<128, 256, 0, stream>>>(pooled, gamma0, beta0, nullptr, xn1, NG, 128);

    // layer 2: h2 = relu(prop(h1) @ W_gcnx^T + b) (128->156)
    k_prop_t<128><<<cdiv(NN, 4), 256, 0, stream>>>(bufB, off_f, csrc_f, csw_f, dinv_f, nullptr, bufA, NN, 0);
    k_gemm_big<128><<<dim3(cdiv(NN, GBM), cdiv(156, GBN)), 256, 0, stream>>>(bufA, W_gcnx, b_gcnx, bufB, NN, 156, 1);
    k_pool<<<NG, 256, 0, stream>>>(bufB, goff, pooled, 156);
    k_bn<<<156, 256, 0, stream>>>(pooled, gamma1, beta1, nullptr, xn2, NG, 156);

    // layer 3: h3 = relu(prop(h2) @ W_gcny^T + b) (156->184)
    k_prop_t<156><<<cdiv(NN, 4), 256, 0, stream>>>(bufB, off_f, csrc_f, csw_f, dinv_f, nullptr, bufA, NN, 0);
    k_gemm_big<156><<<dim3(cdiv(NN, GBM), cdiv(184, GBN)), 256, 0, stream>>>(bufA, W_gcny, b_gcny, bufB, NN, 184, 1);
    k_pool<<<NG, 256, 0, stream>>>(bufB, goff, pooled, 184);
    k_bn<<<184, 256, 0, stream>>>(pooled, gamma2, beta2, nullptr, xn3, NG, 184);

    // ==== coarse chain (K=2 props) ====
    // g1: h = bn(relu(prop^2(xn1) @ Wg1^T + b)) + xn2
    k_prop_t<128><<<cdiv(NG, 4), 256, 0, stream>>>(xn1, off_g, csrc_g, csw_g, dinv_g, nullptr, ctA, NG, 0);
    k_prop_t<128><<<cdiv(NG, 4), 256, 0, stream>>>(ctA, off_g, csrc_g, csw_g, dinv_g, nullptr, ctB, NG, 0);
    k_gemm<<<dim3(cdiv(NG, BM), cdiv(156, BN)), 256, 0, stream>>>(ctB, W_g1, b_g1, ctA, NG, 128, 156, 1);
    k_bn<<<156, 256, 0, stream>>>(ctA, gamma1, beta1, xn2, ctB, NG, 156);
    // g2
    k_prop_t<156><<<cdiv(NG, 4), 256, 0, stream>>>(ctB, off_g, csrc_g, csw_g, dinv_g, nullptr, ctA, NG, 0);
    k_prop_t<156><<<cdiv(NG, 4), 256, 0, stream>>>(ctA, off_g, csrc_g, csw_g, dinv_g, nullptr, ctB, NG, 0);
    k_gemm<<<dim3(cdiv(NG, BM), cdiv(184, BN)), 256, 0, stream>>>(ctB, W_g2, b_g2, ctA, NG, 156, 184, 1);
    k_bn<<<184, 256, 0, stream>>>(ctA, gamma2, beta2, xn3, ctB, NG, 184);
    // g3
    k_prop_t<184><<<cdiv(NG, 4), 256, 0, stream>>>(ctB, off_g, csrc_g, csw_g, dinv_g, nullptr, ctA, NG, 0);
    k_prop_t<184><<<cdiv(NG, 4), 256, 0, stream>>>(ctA, off_g, csrc_g, csw_g, dinv_g, nullptr, ctB, NG, 0);
    k_gemm<<<dim3(cdiv(NG, BM), cdiv(212, BN)), 256, 0, stream>>>(ctB, W_g3, b_g3, ctA, NG, 184, 212, 1);
    k_bn<<<212, 256, 0, stream>>>(ctA, gamma3, beta3, nullptr, ctB, NG, 212);

    // ==== classifier ====
    k_gemm<<<dim3(cdiv(NG, BM), cdiv(106, BN)), 256, 0, stream>>>(ctB, Wc1, bc1, ctA, NG, 212, 106, 1);
    k_gemm<<<dim3(cdiv(NG, BM), cdiv(16, BN)), 256, 0, stream>>>(ctA, Wc2, bc2, outp, NG, 106, 16, 0);
}

// Round 10
// 1456.244 us; speedup vs baseline: 1.0558x; 1.0558x over previous
//
#include <hip/hip_runtime.h>

// Problem constants (fixed by reference)
#define NN 100000
#define NE 1600000
#define NG 2000
#define NFE 32000

#define SCAN_CHUNK 2048
#define SCAN_T 256
#define SCAN_V 8

// ---------------- histogram / degree ----------------
__global__ void k_count(const int* __restrict__ ids, int* __restrict__ counts, int n) {
    int i = blockIdx.x * blockDim.x + threadIdx.x;
    if (i < n) atomicAdd(&counts[ids[i]], 1);
}

__global__ void k_dinv(const int* __restrict__ counts, float* __restrict__ dinv, int n) {
    int i = blockIdx.x * blockDim.x + threadIdx.x;
    if (i < n) dinv[i] = rsqrtf((float)counts[i] + 1.0f);
}

// ---------------- 3-kernel exclusive scan ----------------
__global__ void k_scan_partial(const int* __restrict__ in, int* __restrict__ part, int n) {
    __shared__ int red[SCAN_T];
    int t = threadIdx.x;
    int base = blockIdx.x * SCAN_CHUNK + t * SCAN_V;
    int s = 0;
#pragma unroll
    for (int j = 0; j < SCAN_V; j++) {
        int idx = base + j;
        if (idx < n) s += in[idx];
    }
    red[t] = s;
    __syncthreads();
    for (int st = SCAN_T / 2; st > 0; st >>= 1) {
        if (t < st) red[t] += red[t + st];
        __syncthreads();
    }
    if (t == 0) part[blockIdx.x] = red[0];
}

// single block: exclusive scan of part[0..nb) in place (nb <= 256)
__global__ void k_scan_small(int* __restrict__ part, int nb) {
    __shared__ int sh[SCAN_T];
    int t = threadIdx.x;
    int v = (t < nb) ? part[t] : 0;
    sh[t] = v;
    __syncthreads();
    for (int st = 1; st < SCAN_T; st <<= 1) {
        int x = (t >= st) ? sh[t - st] : 0;
        __syncthreads();
        sh[t] += x;
        __syncthreads();
    }
    if (t < nb) part[t] = sh[t] - v;  // exclusive
}

__global__ void k_scan_apply(const int* __restrict__ in, const int* __restrict__ part,
                             int* __restrict__ out, int* __restrict__ out2, int n) {
    __shared__ int red[SCAN_T];
    int t = threadIdx.x;
    int base = blockIdx.x * SCAN_CHUNK + t * SCAN_V;
    int vals[SCAN_V];
    int s = 0;
#pragma unroll
    for (int j = 0; j < SCAN_V; j++) {
        int idx = base + j;
        vals[j] = (idx < n) ? in[idx] : 0;
        s += vals[j];
    }
    red[t] = s;
    __syncthreads();
    for (int st = 1; st < SCAN_T; st <<= 1) {
        int x = (t >= st) ? red[t - st] : 0;
        __syncthreads();
        red[t] += x;
        __syncthreads();
    }
    int texcl = red[t] - s;
    int run = part[blockIdx.x] + texcl;
#pragma unroll
    for (int j = 0; j < SCAN_V; j++) {
        int idx = base + j;
        if (idx < n) {
            out[idx] = run;
            if (out2) out2[idx] = run;
            run += vals[j];
            if (idx == n - 1) {  // write total at position n
                out[n] = run;
                if (out2) out2[n] = run;
            }
        }
    }
}

// ---------------- CSR fill ----------------
__global__ void k_fill(const int* __restrict__ src, const int* __restrict__ dst,
                       const float* __restrict__ dinv, int* __restrict__ cursor,
                       int* __restrict__ csr_src, float* __restrict__ csr_w, int n) {
    int i = blockIdx.x * blockDim.x + threadIdx.x;
    if (i < n) {
        int s = src[i], d = dst[i];
        int pos = atomicAdd(&cursor[d], 1);
        csr_src[pos] = s;
        csr_w[pos] = dinv[s] * dinv[d];
    }
}

// ---------------- propagation: out[n] = dinv[n]^2 * x[n] + sum_e w_e * x[src_e] ----------------
// one wave per node; lanes cover channels via float2; edge loop unrolled x4 for MLP.
template <int C>
__global__ void k_prop_t(const float* __restrict__ x, const int* __restrict__ off,
                         const int* __restrict__ srcs, const float* __restrict__ w,
                         const float* __restrict__ dinv, const float* __restrict__ bias,
                         float* __restrict__ out, int n, int relu) {
    constexpr int NCH = C / 128;      // full 128-float chunks (64 float2 lanes each)
    constexpr int REM = C % 128;      // remainder floats (even for all our C)
    constexpr int NACC = NCH + (REM ? 1 : 0);
    int node = (int)((blockIdx.x * (size_t)blockDim.x + threadIdx.x) >> 6);
    int lane = threadIdx.x & 63;
    if (node >= n) return;
    float dv = dinv[node];
    float sw = dv * dv;
    const float2* xr = (const float2*)(x + (size_t)node * C);
    bool remAct = (REM != 0) && (lane * 2 < REM);
    float2 acc[NACC];
#pragma unroll
    for (int j = 0; j < NCH; j++) {
        float2 v = xr[lane + 64 * j];
        acc[j].x = sw * v.x; acc[j].y = sw * v.y;
    }
    if (REM) {
        acc[NCH].x = 0.f; acc[NCH].y = 0.f;
        if (remAct) {
            float2 v = xr[NCH * 64 + lane];
            acc[NCH].x = sw * v.x; acc[NCH].y = sw * v.y;
        }
    }
    int e0 = off[node], e1 = off[node + 1];
    int e = e0;
    // unrolled by 4: issue all 4 index loads, then all 4*NACC row gathers, then FMAs
    for (; e + 4 <= e1; e += 4) {
        int s0 = srcs[e + 0], s1 = srcs[e + 1], s2 = srcs[e + 2], s3 = srcs[e + 3];
        float w0 = w[e + 0], w1 = w[e + 1], w2 = w[e + 2], w3 = w[e + 3];
        const float2* p0 = (const float2*)(x + (size_t)s0 * C);
        const float2* p1 = (const float2*)(x + (size_t)s1 * C);
        const float2* p2 = (const float2*)(x + (size_t)s2 * C);
        const float2* p3 = (const float2*)(x + (size_t)s3 * C);
#pragma unroll
        for (int j = 0; j < NCH; j++) {
            int idx = lane + 64 * j;
            float2 v0 = p0[idx];
            float2 v1 = p1[idx];
            float2 v2 = p2[idx];
            float2 v3 = p3[idx];
            acc[j].x += w0 * v0.x + w1 * v1.x + w2 * v2.x + w3 * v3.x;
            acc[j].y += w0 * v0.y + w1 * v1.y + w2 * v2.y + w3 * v3.y;
        }
        if (REM && remAct) {
            int idx = NCH * 64 + lane;
            float2 v0 = p0[idx];
            float2 v1 = p1[idx];
            float2 v2 = p2[idx];
            float2 v3 = p3[idx];
            acc[NCH].x += w0 * v0.x + w1 * v1.x + w2 * v2.x + w3 * v3.x;
            acc[NCH].y += w0 * v0.y + w1 * v1.y + w2 * v2.y + w3 * v3.y;
        }
    }
    for (; e < e1; e++) {
        int s = srcs[e];
        float ww = w[e];
        const float2* xs = (const float2*)(x + (size_t)s * C);
#pragma unroll
        for (int j = 0; j < NCH; j++) {
            float2 v = xs[lane + 64 * j];
            acc[j].x += ww * v.x; acc[j].y += ww * v.y;
        }
        if (REM && remAct) {
            float2 v = xs[NCH * 64 + lane];
            acc[NCH].x += ww * v.x; acc[NCH].y += ww * v.y;
        }
    }
    float2* orow = (float2*)(out + (size_t)node * C);
#pragma unroll
    for (int j = 0; j < NCH; j++) {
        int idx = lane + 64 * j;
        float2 v = acc[j];
        if (bias) { v.x += bias[idx * 2]; v.y += bias[idx * 2 + 1]; }
        if (relu) { v.x = fmaxf(v.x, 0.f); v.y = fmaxf(v.y, 0.f); }
        orow[idx] = v;
    }
    if (REM && remAct) {
        int idx = NCH * 64 + lane;
        float2 v = acc[NCH];
        if (bias) { v.x += bias[idx * 2]; v.y += bias[idx * 2 + 1]; }
        if (relu) { v.x = fmaxf(v.x, 0.f); v.y = fmaxf(v.y, 0.f); }
        orow[idx] = v;
    }
}

// ---------------- big GEMM: out[M,O] = A[M,K] @ W[O,K]^T (+bias, relu) ----------------
// 128x128 tile, 8x8 per thread, BK=16, float4 staging. K constexpr, K%4==0, O%4==0.
#define GBM 128
#define GBN 128
#define GBK 16
template <int K>
__global__ __launch_bounds__(256) void k_gemm_big(const float* __restrict__ A, const float* __restrict__ W,
                                                  const float* __restrict__ bias, float* __restrict__ out,
                                                  int M, int O, int relu) {
    __shared__ float As[GBK][GBM + 4];
    __shared__ float Bs[GBK][GBN + 4];
    int tid = threadIdx.x;
    int tx = tid & 15;        // 16 col groups of 8
    int ty = tid >> 4;        // 16 row groups of 8
    int row0 = blockIdx.x * GBM, col0 = blockIdx.y * GBN;
    float acc[8][8] = {};
    for (int k0 = 0; k0 < K; k0 += GBK) {
        // stage A: 128 rows x 16 k = 512 float4 -> 2 per thread
#pragma unroll
        for (int l = 0; l < 2; l++) {
            int idx = tid + l * 256;
            int m = idx >> 2, kq = idx & 3;
            int r = row0 + m, k = k0 + kq * 4;
            float4 v = {0.f, 0.f, 0.f, 0.f};
            if (r < M && k < K) v = *(const float4*)(A + (size_t)r * K + k);
            As[kq * 4 + 0][m] = v.x;
            As[kq * 4 + 1][m] = v.y;
            As[kq * 4 + 2][m] = v.z;
            As[kq * 4 + 3][m] = v.w;
        }
        // stage B: 128 out-cols x 16 k = 512 float4 -> 2 per thread
#pragma unroll
        for (int l = 0; l < 2; l++) {
            int idx = tid + l * 256;
            int m = idx >> 2, kq = idx & 3;
            int c = col0 + m, k = k0 + kq * 4;
            float4 v = {0.f, 0.f, 0.f, 0.f};
            if (c < O && k < K) v = *(const float4*)(W + (size_t)c * K + k);
            Bs[kq * 4 + 0][m] = v.x;
            Bs[kq * 4 + 1][m] = v.y;
            Bs[kq * 4 + 2][m] = v.z;
            Bs[kq * 4 + 3][m] = v.w;
        }
        __syncthreads();
#pragma unroll
        for (int kk = 0; kk < GBK; kk++) {
            float a[8], b[8];
#pragma unroll
            for (int i = 0; i < 8; i++) a[i] = As[kk][ty * 8 + i];
#pragma unroll
            for (int j = 0; j < 8; j++) b[j] = Bs[kk][tx * 8 + j];
#pragma unroll
            for (int i = 0; i < 8; i++)
#pragma unroll
                for (int j = 0; j < 8; j++) acc[i][j] += a[i] * b[j];
        }
        __syncthreads();
    }
    // writeback: 8 rows x 2 float4
    float4 bv0 = {0.f, 0.f, 0.f, 0.f}, bv1 = {0.f, 0.f, 0.f, 0.f};
    int c0 = col0 + tx * 8, c1 = c0 + 4;
    if (bias) {
        if (c0 < O) bv0 = *(const float4*)(bias + c0);
        if (c1 < O) bv1 = *(const float4*)(bias + c1);
    }
#pragma unroll
    for (int i = 0; i < 8; i++) {
        int r = row0 + ty * 8 + i;
        if (r >= M) continue;
        if (c0 < O) {
            float4 v = {acc[i][0] + bv0.x, acc[i][1] + bv0.y, acc[i][2] + bv0.z, acc[i][3] + bv0.w};
            if (relu) { v.x = fmaxf(v.x, 0.f); v.y = fmaxf(v.y, 0.f); v.z = fmaxf(v.z, 0.f); v.w = fmaxf(v.w, 0.f); }
            *(float4*)(out + (size_t)r * O + c0) = v;
        }
        if (c1 < O) {
            float4 v = {acc[i][4] + bv1.x, acc[i][5] + bv1.y, acc[i][6] + bv1.z, acc[i][7] + bv1.w};
            if (relu) { v.x = fmaxf(v.x, 0.f); v.y = fmaxf(v.y, 0.f); v.z = fmaxf(v.z, 0.f); v.w = fmaxf(v.w, 0.f); }
            *(float4*)(out + (size_t)r * O + c1) = v;
        }
    }
}

// ---------------- small GEMM: out[M,O] = A[M,K] @ W[O,K]^T (+bias, relu) ----------------
#define BM 64
#define BN 64
#define BK 16
__global__ __launch_bounds__(256) void k_gemm(const float* __restrict__ A, const float* __restrict__ W,
                                              const float* __restrict__ bias, float* __restrict__ out,
                                              int M, int K, int O, int relu) {
    __shared__ float As[BK][BM + 4];
    __shared__ float Bs[BK][BN + 4];
    int tid = threadIdx.x;
    int tx = tid % 16, ty = tid / 16;
    int row0 = blockIdx.x * BM, col0 = blockIdx.y * BN;
    float acc[4][4] = {};
    for (int k0 = 0; k0 < K; k0 += BK) {
        for (int t = tid; t < BM * BK; t += 256) {
            int m = t / BK, kk = t % BK;
            float v = 0.f;
            int r = row0 + m, k = k0 + kk;
            if (r < M && k < K) v = A[(size_t)r * K + k];
            As[kk][m] = v;
        }
        for (int t = tid; t < BN * BK; t += 256) {
            int o = t / BK, kk = t % BK;
            float v = 0.f;
            int c = col0 + o, k = k0 + kk;
            if (c < O && k < K) v = W[(size_t)c * K + k];
            Bs[kk][o] = v;
        }
        __syncthreads();
#pragma unroll
        for (int kk = 0; kk < BK; kk++) {
            float a[4], b[4];
#pragma unroll
            for (int i = 0; i < 4; i++) a[i] = As[kk][ty * 4 + i];
#pragma unroll
            for (int j = 0; j < 4; j++) b[j] = Bs[kk][tx * 4 + j];
#pragma unroll
            for (int i = 0; i < 4; i++)
#pragma unroll
                for (int j = 0; j < 4; j++) acc[i][j] += a[i] * b[j];
        }
        __syncthreads();
    }
#pragma unroll
    for (int i = 0; i < 4; i++) {
        int r = row0 + ty * 4 + i;
        if (r >= M) continue;
#pragma unroll
        for (int j = 0; j < 4; j++) {
            int c = col0 + tx * 4 + j;
            if (c >= O) continue;
            float v = acc[i][j] + (bias ? bias[c] : 0.f);
            if (relu) v = fmaxf(v, 0.f);
            out[(size_t)r * O + c] = v;
        }
    }
}

// ---------------- mean pool (batch sorted -> contiguous segments) ----------------
__global__ void k_pool(const float* __restrict__ x, const int* __restrict__ goff,
                       float* __restrict__ out, int C) {
    int g = blockIdx.x;
    int c = threadIdx.x;
    if (c >= C) return;
    int r0 = goff[g], r1 = goff[g + 1];
    float s = 0.f;
    for (int r = r0; r < r1; r++) s += x[(size_t)r * C + c];
    float cnt = (float)(r1 - r0);
    out[(size_t)g * C + c] = s / fmaxf(cnt, 1.0f);
}

// ---------------- batchnorm over rows (per column stats), optional residual add ----------------
__global__ void k_bn(const float* __restrict__ x, const float* __restrict__ gamma,
                     const float* __restrict__ beta, const float* __restrict__ residual,
                     float* __restrict__ out, int G_, int C) {
    int c = blockIdx.x;
    __shared__ float red[256];
    int t = threadIdx.x;
    float s = 0.f;
    for (int r = t; r < G_; r += 256) s += x[(size_t)r * C + c];
    red[t] = s;
    __syncthreads();
    for (int st = 128; st > 0; st >>= 1) {
        if (t < st) red[t] += red[t + st];
        __syncthreads();
    }
    float mean = red[0] / (float)G_;
    __syncthreads();
    float v = 0.f;
    for (int r = t; r < G_; r += 256) {
        float d = x[(size_t)r * C + c] - mean;
        v += d * d;
    }
    red[t] = v;
    __syncthreads();
    for (int st = 128; st > 0; st >>= 1) {
        if (t < st) red[t] += red[t + st];
        __syncthreads();
    }
    float var = red[0] / (float)G_;
    float scale = rsqrtf(var + 1e-5f) * gamma[c];
    float shift = beta[c];
    for (int r = t; r < G_; r += 256) {
        float o = (x[(size_t)r * C + c] - mean) * scale + shift;
        if (residual) o += residual[(size_t)r * C + c];
        out[(size_t)r * C + c] = o;
    }
}

extern "C" void kernel_launch(void* const* d_in, const int* in_sizes, int n_in,
                              void* d_out, int out_size, void* d_ws, size_t ws_size,
                              hipStream_t stream) {
    (void)in_sizes; (void)n_in; (void)out_size; (void)ws_size;
    const float* x      = (const float*)d_in[0];
    const int*   ei     = (const int*)d_in[1];   // [2, NE]
    const int*   batch  = (const int*)d_in[2];
    const int*   fei    = (const int*)d_in[3];   // [2, NFE]
    const float* W_gcn  = (const float*)d_in[4];  const float* b_gcn  = (const float*)d_in[5];
    const float* W_gcnx = (const float*)d_in[6];  const float* b_gcnx = (const float*)d_in[7];
    const float* W_gcny = (const float*)d_in[8];  const float* b_gcny = (const float*)d_in[9];
    const float* W_g1   = (const float*)d_in[10]; const float* b_g1   = (const float*)d_in[11];
    const float* W_g2   = (const float*)d_in[12]; const float* b_g2   = (const float*)d_in[13];
    const float* W_g3   = (const float*)d_in[14]; const float* b_g3   = (const float*)d_in[15];
    const float* gamma0 = (const float*)d_in[16]; const float* beta0  = (const float*)d_in[17];
    const float* gamma1 = (const float*)d_in[18]; const float* beta1  = (const float*)d_in[19];
    const float* gamma2 = (const float*)d_in[20]; const float* beta2  = (const float*)d_in[21];
    const float* gamma3 = (const float*)d_in[22]; const float* beta3  = (const float*)d_in[23];
    const float* Wc1    = (const float*)d_in[24]; const float* bc1    = (const float*)d_in[25];
    const float* Wc2    = (const float*)d_in[26]; const float* bc2    = (const float*)d_in[27];
    float* outp = (float*)d_out;

    char* ws = (char*)d_ws;
    size_t off = 0;
    auto alloc = [&](size_t bytes) -> char* {
        char* p = ws + off;
        off = (off + bytes + 255) & ~(size_t)255;
        return p;
    };

    int*   counts_f = (int*)alloc((size_t)NN * 4);
    int*   off_f    = (int*)alloc((size_t)(NN + 1) * 4);
    int*   cur_f    = (int*)alloc((size_t)(NN + 1) * 4);
    int*   csrc_f   = (int*)alloc((size_t)NE * 4);
    float* csw_f    = (float*)alloc((size_t)NE * 4);
    float* dinv_f   = (float*)alloc((size_t)NN * 4);

    int*   counts_g = (int*)alloc((size_t)NG * 4);
    int*   off_g    = (int*)alloc((size_t)(NG + 1) * 4);
    int*   cur_g    = (int*)alloc((size_t)(NG + 1) * 4);
    int*   csrc_g   = (int*)alloc((size_t)NFE * 4);
    float* csw_g    = (float*)alloc((size_t)NFE * 4);
    float* dinv_g   = (float*)alloc((size_t)NG * 4);

    int*   gcnt = (int*)alloc((size_t)NG * 4);
    int*   goff = (int*)alloc((size_t)(NG + 1) * 4);
    int*   part = (int*)alloc(1024 * 4);

    float* bufA   = (float*)alloc((size_t)NN * 156 * 4);
    float* bufB   = (float*)alloc((size_t)NN * 184 * 4);
    float* pooled = (float*)alloc((size_t)NG * 184 * 4);
    float* xn1    = (float*)alloc((size_t)NG * 128 * 4);
    float* xn2    = (float*)alloc((size_t)NG * 156 * 4);
    float* xn3    = (float*)alloc((size_t)NG * 184 * 4);
    float* ctA    = (float*)alloc((size_t)NG * 212 * 4);
    float* ctB    = (float*)alloc((size_t)NG * 212 * 4);

    auto cdiv = [](int a, int b) { return (a + b - 1) / b; };

    hipMemsetAsync(counts_f, 0, (size_t)NN * 4, stream);
    hipMemsetAsync(counts_g, 0, (size_t)NG * 4, stream);
    hipMemsetAsync(gcnt,     0, (size_t)NG * 4, stream);

    // ---- fine graph CSR ----
    k_count<<<cdiv(NE, 256), 256, 0, stream>>>(ei + NE, counts_f, NE);
    k_dinv<<<cdiv(NN, 256), 256, 0, stream>>>(counts_f, dinv_f, NN);
    int nbN = cdiv(NN, SCAN_CHUNK);
    k_scan_partial<<<nbN, SCAN_T, 0, stream>>>(counts_f, part, NN);
    k_scan_small<<<1, SCAN_T, 0, stream>>>(part, nbN);
    k_scan_apply<<<nbN, SCAN_T, 0, stream>>>(counts_f, part, off_f, cur_f, NN);
    k_fill<<<cdiv(NE, 256), 256, 0, stream>>>(ei, ei + NE, dinv_f, cur_f, csrc_f, csw_f, NE);

    // ---- full (coarse) graph CSR ----
    k_count<<<cdiv(NFE, 256), 256, 0, stream>>>(fei + NFE, counts_g, NFE);
    k_dinv<<<cdiv(NG, 256), 256, 0, stream>>>(counts_g, dinv_g, NG);
    int nbG = cdiv(NG, SCAN_CHUNK);
    k_scan_partial<<<nbG, SCAN_T, 0, stream>>>(counts_g, part, NG);
    k_scan_small<<<1, SCAN_T, 0, stream>>>(part, nbG);
    k_scan_apply<<<nbG, SCAN_T, 0, stream>>>(counts_g, part, off_g, cur_g, NG);
    k_fill<<<cdiv(NFE, 256), 256, 0, stream>>>(fei, fei + NFE, dinv_g, cur_g, csrc_g, csw_g, NFE);

    // ---- pooling offsets from sorted batch ----
    k_count<<<cdiv(NN, 256), 256, 0, stream>>>(batch, gcnt, NN);
    k_scan_partial<<<nbG, SCAN_T, 0, stream>>>(gcnt, part, NG);
    k_scan_small<<<1, SCAN_T, 0, stream>>>(part, nbG);
    k_scan_apply<<<nbG, SCAN_T, 0, stream>>>(gcnt, part, goff, nullptr, NG);

    // ==== fine branch ====
    // layer 1: t = x @ W_gcn^T (200->128), then h1 = relu(prop(t) + b_gcn)
    k_gemm_big<200><<<dim3(cdiv(NN, GBM), cdiv(128, GBN)), 256, 0, stream>>>(x, W_gcn, nullptr, bufA, NN, 128, 0);
    k_prop_t<128><<<cdiv(NN, 4), 256, 0, stream>>>(bufA, off_f, csrc_f, csw_f, dinv_f, b_gcn, bufB, NN, 1);
    k_pool<<<NG, 256, 0, stream>>>(bufB, goff, pooled, 128);
    k_bn<<<128, 256, 0, stream>>>(pooled, gamma0, beta0, nullptr, xn1, NG, 128);

    // layer 2: h2 = relu(prop(h1) @ W_gcnx^T + b) (128->156)
    k_prop_t<128><<<cdiv(NN, 4), 256, 0, stream>>>(bufB, off_f, csrc_f, csw_f, dinv_f, nullptr, bufA, NN, 0);
    k_gemm_big<128><<<dim3(cdiv(NN, GBM), cdiv(156, GBN)), 256, 0, stream>>>(bufA, W_gcnx, b_gcnx, bufB, NN, 156, 1);
    k_pool<<<NG, 256, 0, stream>>>(bufB, goff, pooled, 156);
    k_bn<<<156, 256, 0, stream>>>(pooled, gamma1, beta1, nullptr, xn2, NG, 156);

    // layer 3: h3 = relu(prop(h2) @ W_gcny^T + b) (156->184)
    k_prop_t<156><<<cdiv(NN, 4), 256, 0, stream>>>(bufB, off_f, csrc_f, csw_f, dinv_f, nullptr, bufA, NN, 0);
    k_gemm_big<156><<<dim3(cdiv(NN, GBM), cdiv(184, GBN)), 256, 0, stream>>>(bufA, W_gcny, b_gcny, bufB, NN, 184, 1);
    k_pool<<<NG, 256, 0, stream>>>(bufB, goff, pooled, 184);
    k_bn<<<184, 256, 0, stream>>>(pooled, gamma2, beta2, nullptr, xn3, NG, 184);

    // ==== coarse chain (K=2 props) ====
    // g1: h = bn(relu(prop^2(xn1) @ Wg1^T + b)) + xn2
    k_prop_t<128><<<cdiv(NG, 4), 256, 0, stream>>>(xn1, off_g, csrc_g, csw_g, dinv_g, nullptr, ctA, NG, 0);
    k_prop_t<128><<<cdiv(NG, 4), 256, 0, stream>>>(ctA, off_g, csrc_g, csw_g, dinv_g, nullptr, ctB, NG, 0);
    k_gemm<<<dim3(cdiv(NG, BM), cdiv(156, BN)), 256, 0, stream>>>(ctB, W_g1, b_g1, ctA, NG, 128, 156, 1);
    k_bn<<<156, 256, 0, stream>>>(ctA, gamma1, beta1, xn2, ctB, NG, 156);
    // g2
    k_prop_t<156><<<cdiv(NG, 4), 256, 0, stream>>>(ctB, off_g, csrc_g, csw_g, dinv_g, nullptr, ctA, NG, 0);
    k_prop_t<156><<<cdiv(NG, 4), 256, 0, stream>>>(ctA, off_g, csrc_g, csw_g, dinv_g, nullptr, ctB, NG, 0);
    k_gemm<<<dim3(cdiv(NG, BM), cdiv(184, BN)), 256, 0, stream>>>(ctB, W_g2, b_g2, ctA, NG, 156, 184, 1);
    k_bn<<<184, 256, 0, stream>>>(ctA, gamma2, beta2, xn3, ctB, NG, 184);
    // g3
    k_prop_t<184><<<cdiv(NG, 4), 256, 0, stream>>>(ctB, off_g, csrc_g, csw_g, dinv_g, nullptr, ctA, NG, 0);
    k_prop_t<184><<<cdiv(NG, 4), 256, 0, stream>>>(ctA, off_g, csrc_g, csw_g, dinv_g, nullptr, ctB, NG, 0);
    k_gemm<<<dim3(cdiv(NG, BM), cdiv(212, BN)), 256, 0, stream>>>(ctB, W_g3, b_g3, ctA, NG, 184, 212, 1);
    k_bn<<<212, 256, 0, stream>>>(ctA, gamma3, beta3, nullptr, ctB, NG, 212);

    // ==== classifier ====
    k_gemm<<<dim3(cdiv(NG, BM), cdiv(106, BN)), 256, 0, stream>>>(ctB, Wc1, bc1, ctA, NG, 212, 106, 1);
    k_gemm<<<dim3(cdiv(NG, BM), cdiv(16, BN)), 256, 0, stream>>>(ctA, Wc2, bc2, outp, NG, 106, 16, 0);
}

// Round 13
// 1341.145 us; speedup vs baseline: 1.1464x; 1.0858x over previous
//
#include <hip/hip_runtime.h>
#include <hip/hip_fp16.h>

// Problem constants (fixed by reference)
#define NN 100000
#define NE 1600000
#define NG 2000
#define NFE 32000

#define SCAN_CHUNK 2048
#define SCAN_T 256
#define SCAN_V 8

// ---------------- histogram / degree ----------------
__global__ void k_count(const int* __restrict__ ids, int* __restrict__ counts, int n) {
    int i = blockIdx.x * blockDim.x + threadIdx.x;
    if (i < n) atomicAdd(&counts[ids[i]], 1);
}

__global__ void k_dinv(const int* __restrict__ counts, float* __restrict__ dinv, int n) {
    int i = blockIdx.x * blockDim.x + threadIdx.x;
    if (i < n) dinv[i] = rsqrtf((float)counts[i] + 1.0f);
}

// ---------------- fp32 -> fp16 convert (4 floats / thread) ----------------
__global__ void k_cvt(const float* __restrict__ in, __half* __restrict__ out, size_t n4) {
    size_t i = (size_t)blockIdx.x * blockDim.x + threadIdx.x;
    if (i < n4) {
        float4 v = *(const float4*)(in + i * 4);
        __half2* o = (__half2*)(out + i * 4);
        o[0] = __floats2half2_rn(v.x, v.y);
        o[1] = __floats2half2_rn(v.z, v.w);
    }
}

// ---------------- 3-kernel exclusive scan ----------------
__global__ void k_scan_partial(const int* __restrict__ in, int* __restrict__ part, int n) {
    __shared__ int red[SCAN_T];
    int t = threadIdx.x;
    int base = blockIdx.x * SCAN_CHUNK + t * SCAN_V;
    int s = 0;
#pragma unroll
    for (int j = 0; j < SCAN_V; j++) {
        int idx = base + j;
        if (idx < n) s += in[idx];
    }
    red[t] = s;
    __syncthreads();
    for (int st = SCAN_T / 2; st > 0; st >>= 1) {
        if (t < st) red[t] += red[t + st];
        __syncthreads();
    }
    if (t == 0) part[blockIdx.x] = red[0];
}

// single block: exclusive scan of part[0..nb) in place (nb <= 256)
__global__ void k_scan_small(int* __restrict__ part, int nb) {
    __shared__ int sh[SCAN_T];
    int t = threadIdx.x;
    int v = (t < nb) ? part[t] : 0;
    sh[t] = v;
    __syncthreads();
    for (int st = 1; st < SCAN_T; st <<= 1) {
        int x = (t >= st) ? sh[t - st] : 0;
        __syncthreads();
        sh[t] += x;
        __syncthreads();
    }
    if (t < nb) part[t] = sh[t] - v;  // exclusive
}

__global__ void k_scan_apply(const int* __restrict__ in, const int* __restrict__ part,
                             int* __restrict__ out, int* __restrict__ out2, int n) {
    __shared__ int red[SCAN_T];
    int t = threadIdx.x;
    int base = blockIdx.x * SCAN_CHUNK + t * SCAN_V;
    int vals[SCAN_V];
    int s = 0;
#pragma unroll
    for (int j = 0; j < SCAN_V; j++) {
        int idx = base + j;
        vals[j] = (idx < n) ? in[idx] : 0;
        s += vals[j];
    }
    red[t] = s;
    __syncthreads();
    for (int st = 1; st < SCAN_T; st <<= 1) {
        int x = (t >= st) ? red[t - st] : 0;
        __syncthreads();
        red[t] += x;
        __syncthreads();
    }
    int texcl = red[t] - s;
    int run = part[blockIdx.x] + texcl;
#pragma unroll
    for (int j = 0; j < SCAN_V; j++) {
        int idx = base + j;
        if (idx < n) {
            out[idx] = run;
            if (out2) out2[idx] = run;
            run += vals[j];
            if (idx == n - 1) {  // write total at position n
                out[n] = run;
                if (out2) out2[n] = run;
            }
        }
    }
}

// ---------------- CSR fill ----------------
__global__ void k_fill(const int* __restrict__ src, const int* __restrict__ dst,
                       const float* __restrict__ dinv, int* __restrict__ cursor,
                       int* __restrict__ csr_src, float* __restrict__ csr_w, int n) {
    int i = blockIdx.x * blockDim.x + threadIdx.x;
    if (i < n) {
        int s = src[i], d = dst[i];
        int pos = atomicAdd(&cursor[d], 1);
        csr_src[pos] = s;
        csr_w[pos] = dinv[s] * dinv[d];
    }
}

// ---------------- propagation: out[n] = dinv[n]^2 * x[n] + sum_e w_e * x[src_e] ----------------
// one wave per node; lanes cover channels; edge loop unrolled x4 for MLP.
// H=true: gathers read the fp16 copy xh (half traffic); self-term/bias/accum/output stay fp32.
template <int C, bool H>
__global__ void k_prop_t(const float* __restrict__ x, const __half* __restrict__ xh,
                         const int* __restrict__ off,
                         const int* __restrict__ srcs, const float* __restrict__ w,
                         const float* __restrict__ dinv, const float* __restrict__ bias,
                         float* __restrict__ out, int n, int relu) {
    constexpr int NCH = C / 128;      // full 128-elem chunks (64 lanes x 2 elems)
    constexpr int REM = C % 128;      // remainder elems (even for all our C)
    constexpr int NACC = NCH + (REM ? 1 : 0);
    int node = (int)((blockIdx.x * (size_t)blockDim.x + threadIdx.x) >> 6);
    int lane = threadIdx.x & 63;
    if (node >= n) return;
    float dv = dinv[node];
    float sw = dv * dv;
    const float2* xr = (const float2*)(x + (size_t)node * C);
    bool remAct = (REM != 0) && (lane * 2 < REM);
    float2 acc[NACC];
#pragma unroll
    for (int j = 0; j < NCH; j++) {
        float2 v = xr[lane + 64 * j];
        acc[j].x = sw * v.x; acc[j].y = sw * v.y;
    }
    if (REM) {
        acc[NCH].x = 0.f; acc[NCH].y = 0.f;
        if (remAct) {
            float2 v = xr[NCH * 64 + lane];
            acc[NCH].x = sw * v.x; acc[NCH].y = sw * v.y;
        }
    }
    int e0 = off[node], e1 = off[node + 1];
    int e = e0;
    // unrolled by 4: issue all 4 index loads, then all row gathers, then FMAs
    for (; e + 4 <= e1; e += 4) {
        int s0 = srcs[e + 0], s1 = srcs[e + 1], s2 = srcs[e + 2], s3 = srcs[e + 3];
        float w0 = w[e + 0], w1 = w[e + 1], w2 = w[e + 2], w3 = w[e + 3];
        if constexpr (H) {
            const __half2* p0 = (const __half2*)(xh + (size_t)s0 * C);
            const __half2* p1 = (const __half2*)(xh + (size_t)s1 * C);
            const __half2* p2 = (const __half2*)(xh + (size_t)s2 * C);
            const __half2* p3 = (const __half2*)(xh + (size_t)s3 * C);
#pragma unroll
            for (int j = 0; j < NCH; j++) {
                int idx = lane + 64 * j;
                float2 v0 = __half22float2(p0[idx]);
                float2 v1 = __half22float2(p1[idx]);
                float2 v2 = __half22float2(p2[idx]);
                float2 v3 = __half22float2(p3[idx]);
                acc[j].x += w0 * v0.x + w1 * v1.x + w2 * v2.x + w3 * v3.x;
                acc[j].y += w0 * v0.y + w1 * v1.y + w2 * v2.y + w3 * v3.y;
            }
            if (REM && remAct) {
                int idx = NCH * 64 + lane;
                float2 v0 = __half22float2(p0[idx]);
                float2 v1 = __half22float2(p1[idx]);
                float2 v2 = __half22float2(p2[idx]);
                float2 v3 = __half22float2(p3[idx]);
                acc[NCH].x += w0 * v0.x + w1 * v1.x + w2 * v2.x + w3 * v3.x;
                acc[NCH].y += w0 * v0.y + w1 * v1.y + w2 * v2.y + w3 * v3.y;
            }
        } else {
            const float2* p0 = (const float2*)(x + (size_t)s0 * C);
            const float2* p1 = (const float2*)(x + (size_t)s1 * C);
            const float2* p2 = (const float2*)(x + (size_t)s2 * C);
            const float2* p3 = (const float2*)(x + (size_t)s3 * C);
#pragma unroll
            for (int j = 0; j < NCH; j++) {
                int idx = lane + 64 * j;
                float2 v0 = p0[idx];
                float2 v1 = p1[idx];
                float2 v2 = p2[idx];
                float2 v3 = p3[idx];
                acc[j].x += w0 * v0.x + w1 * v1.x + w2 * v2.x + w3 * v3.x;
                acc[j].y += w0 * v0.y + w1 * v1.y + w2 * v2.y + w3 * v3.y;
            }
            if (REM && remAct) {
                int idx = NCH * 64 + lane;
                float2 v0 = p0[idx];
                float2 v1 = p1[idx];
                float2 v2 = p2[idx];
                float2 v3 = p3[idx];
                acc[NCH].x += w0 * v0.x + w1 * v1.x + w2 * v2.x + w3 * v3.x;
                acc[NCH].y += w0 * v0.y + w1 * v1.y + w2 * v2.y + w3 * v3.y;
            }
        }
    }
    for (; e < e1; e++) {
        int s = srcs[e];
        float ww = w[e];
        if constexpr (H) {
            const __half2* xs = (const __half2*)(xh + (size_t)s * C);
#pragma unroll
            for (int j = 0; j < NCH; j++) {
                float2 v = __half22float2(xs[lane + 64 * j]);
                acc[j].x += ww * v.x; acc[j].y += ww * v.y;
            }
            if (REM && remAct) {
                float2 v = __half22float2(xs[NCH * 64 + lane]);
                acc[NCH].x += ww * v.x; acc[NCH].y += ww * v.y;
            }
        } else {
            const float2* xs = (const float2*)(x + (size_t)s * C);
#pragma unroll
            for (int j = 0; j < NCH; j++) {
                float2 v = xs[lane + 64 * j];
                acc[j].x += ww * v.x; acc[j].y += ww * v.y;
            }
            if (REM && remAct) {
                float2 v = xs[NCH * 64 + lane];
                acc[NCH].x += ww * v.x; acc[NCH].y += ww * v.y;
            }
        }
    }
    float2* orow = (float2*)(out + (size_t)node * C);
#pragma unroll
    for (int j = 0; j < NCH; j++) {
        int idx = lane + 64 * j;
        float2 v = acc[j];
        if (bias) { v.x += bias[idx * 2]; v.y += bias[idx * 2 + 1]; }
        if (relu) { v.x = fmaxf(v.x, 0.f); v.y = fmaxf(v.y, 0.f); }
        orow[idx] = v;
    }
    if (REM && remAct) {
        int idx = NCH * 64 + lane;
        float2 v = acc[NCH];
        if (bias) { v.x += bias[idx * 2]; v.y += bias[idx * 2 + 1]; }
        if (relu) { v.x = fmaxf(v.x, 0.f); v.y = fmaxf(v.y, 0.f); }
        orow[idx] = v;
    }
}

// ---------------- big GEMM: out[M,O] = A[M,K] @ W[O,K]^T (+bias, relu) ----------------
// 128x128 tile, 8x8 per thread, BK=16, float4 staging. K constexpr, K%4==0, O%4==0.
#define GBM 128
#define GBN 128
#define GBK 16
template <int K>
__global__ __launch_bounds__(256) void k_gemm_big(const float* __restrict__ A, const float* __restrict__ W,
                                                  const float* __restrict__ bias, float* __restrict__ out,
                                                  int M, int O, int relu) {
    __shared__ float As[GBK][GBM + 4];
    __shared__ float Bs[GBK][GBN + 4];
    int tid = threadIdx.x;
    int tx = tid & 15;        // 16 col groups of 8
    int ty = tid >> 4;        // 16 row groups of 8
    int row0 = blockIdx.x * GBM, col0 = blockIdx.y * GBN;
    float acc[8][8] = {};
    for (int k0 = 0; k0 < K; k0 += GBK) {
        // stage A: 128 rows x 16 k = 512 float4 -> 2 per thread
#pragma unroll
        for (int l = 0; l < 2; l++) {
            int idx = tid + l * 256;
            int m = idx >> 2, kq = idx & 3;
            int r = row0 + m, k = k0 + kq * 4;
            float4 v = {0.f, 0.f, 0.f, 0.f};
            if (r < M && k < K) v = *(const float4*)(A + (size_t)r * K + k);
            As[kq * 4 + 0][m] = v.x;
            As[kq * 4 + 1][m] = v.y;
            As[kq * 4 + 2][m] = v.z;
            As[kq * 4 + 3][m] = v.w;
        }
        // stage B: 128 out-cols x 16 k = 512 float4 -> 2 per thread
#pragma unroll
        for (int l = 0; l < 2; l++) {
            int idx = tid + l * 256;
            int m = idx >> 2, kq = idx & 3;
            int c = col0 + m, k = k0 + kq * 4;
            float4 v = {0.f, 0.f, 0.f, 0.f};
            if (c < O && k < K) v = *(const float4*)(W + (size_t)c * K + k);
            Bs[kq * 4 + 0][m] = v.x;
            Bs[kq * 4 + 1][m] = v.y;
            Bs[kq * 4 + 2][m] = v.z;
            Bs[kq * 4 + 3][m] = v.w;
        }
        __syncthreads();
#pragma unroll
        for (int kk = 0; kk < GBK; kk++) {
            float a[8], b[8];
#pragma unroll
            for (int i = 0; i < 8; i++) a[i] = As[kk][ty * 8 + i];
#pragma unroll
            for (int j = 0; j < 8; j++) b[j] = Bs[kk][tx * 8 + j];
#pragma unroll
            for (int i = 0; i < 8; i++)
#pragma unroll
                for (int j = 0; j < 8; j++) acc[i][j] += a[i] * b[j];
        }
        __syncthreads();
    }
    // writeback: 8 rows x 2 float4
    float4 bv0 = {0.f, 0.f, 0.f, 0.f}, bv1 = {0.f, 0.f, 0.f, 0.f};
    int c0 = col0 + tx * 8, c1 = c0 + 4;
    if (bias) {
        if (c0 < O) bv0 = *(const float4*)(bias + c0);
        if (c1 < O) bv1 = *(const float4*)(bias + c1);
    }
#pragma unroll
    for (int i = 0; i < 8; i++) {
        int r = row0 + ty * 8 + i;
        if (r >= M) continue;
        if (c0 < O) {
            float4 v = {acc[i][0] + bv0.x, acc[i][1] + bv0.y, acc[i][2] + bv0.z, acc[i][3] + bv0.w};
            if (relu) { v.x = fmaxf(v.x, 0.f); v.y = fmaxf(v.y, 0.f); v.z = fmaxf(v.z, 0.f); v.w = fmaxf(v.w, 0.f); }
            *(float4*)(out + (size_t)r * O + c0) = v;
        }
        if (c1 < O) {
            float4 v = {acc[i][4] + bv1.x, acc[i][5] + bv1.y, acc[i][6] + bv1.z, acc[i][7] + bv1.w};
            if (relu) { v.x = fmaxf(v.x, 0.f); v.y = fmaxf(v.y, 0.f); v.z = fmaxf(v.z, 0.f); v.w = fmaxf(v.w, 0.f); }
            *(float4*)(out + (size_t)r * O + c1) = v;
        }
    }
}

// ---------------- small GEMM: out[M,O] = A[M,K] @ W[O,K]^T (+bias, relu) ----------------
#define BM 64
#define BN 64
#define BK 16
__global__ __launch_bounds__(256) void k_gemm(const float* __restrict__ A, const float* __restrict__ W,
                                              const float* __restrict__ bias, float* __restrict__ out,
                                              int M, int K, int O, int relu) {
    __shared__ float As[BK][BM + 4];
    __shared__ float Bs[BK][BN + 4];
    int tid = threadIdx.x;
    int tx = tid % 16, ty = tid / 16;
    int row0 = blockIdx.x * BM, col0 = blockIdx.y * BN;
    float acc[4][4] = {};
    for (int k0 = 0; k0 < K; k0 += BK) {
        for (int t = tid; t < BM * BK; t += 256) {
            int m = t / BK, kk = t % BK;
            float v = 0.f;
            int r = row0 + m, k = k0 + kk;
            if (r < M && k < K) v = A[(size_t)r * K + k];
            As[kk][m] = v;
        }
        for (int t = tid; t < BN * BK; t += 256) {
            int o = t / BK, kk = t % BK;
            float v = 0.f;
            int c = col0 + o, k = k0 + kk;
            if (c < O && k < K) v = W[(size_t)c * K + k];
            Bs[kk][o] = v;
        }
        __syncthreads();
#pragma unroll
        for (int kk = 0; kk < BK; kk++) {
            float a[4], b[4];
#pragma unroll
            for (int i = 0; i < 4; i++) a[i] = As[kk][ty * 4 + i];
#pragma unroll
            for (int j = 0; j < 4; j++) b[j] = Bs[kk][tx * 4 + j];
#pragma unroll
            for (int i = 0; i < 4; i++)
#pragma unroll
                for (int j = 0; j < 4; j++) acc[i][j] += a[i] * b[j];
        }
        __syncthreads();
    }
#pragma unroll
    for (int i = 0; i < 4; i++) {
        int r = row0 + ty * 4 + i;
        if (r >= M) continue;
#pragma unroll
        for (int j = 0; j < 4; j++) {
            int c = col0 + tx * 4 + j;
            if (c >= O) continue;
            float v = acc[i][j] + (bias ? bias[c] : 0.f);
            if (relu) v = fmaxf(v, 0.f);
            out[(size_t)r * O + c] = v;
        }
    }
}

// ---------------- mean pool (batch sorted -> contiguous segments) ----------------
__global__ void k_pool(const float* __restrict__ x, const int* __restrict__ goff,
                       float* __restrict__ out, int C) {
    int g = blockIdx.x;
    int c = threadIdx.x;
    if (c >= C) return;
    int r0 = goff[g], r1 = goff[g + 1];
    float s = 0.f;
    for (int r = r0; r < r1; r++) s += x[(size_t)r * C + c];
    float cnt = (float)(r1 - r0);
    out[(size_t)g * C + c] = s / fmaxf(cnt, 1.0f);
}

// ---------------- batchnorm over rows (per column stats), optional residual add ----------------
__global__ void k_bn(const float* __restrict__ x, const float* __restrict__ gamma,
                     const float* __restrict__ beta, const float* __restrict__ residual,
                     float* __restrict__ out, int G_, int C) {
    int c = blockIdx.x;
    __shared__ float red[256];
    int t = threadIdx.x;
    float s = 0.f;
    for (int r = t; r < G_; r += 256) s += x[(size_t)r * C + c];
    red[t] = s;
    __syncthreads();
    for (int st = 128; st > 0; st >>= 1) {
        if (t < st) red[t] += red[t + st];
        __syncthreads();
    }
    float mean = red[0] / (float)G_;
    __syncthreads();
    float v = 0.f;
    for (int r = t; r < G_; r += 256) {
        float d = x[(size_t)r * C + c] - mean;
        v += d * d;
    }
    red[t] = v;
    __syncthreads();
    for (int st = 128; st > 0; st >>= 1) {
        if (t < st) red[t] += red[t + st];
        __syncthreads();
    }
    float var = red[0] / (float)G_;
    float scale = rsqrtf(var + 1e-5f) * gamma[c];
    float shift = beta[c];
    for (int r = t; r < G_; r += 256) {
        float o = (x[(size_t)r * C + c] - mean) * scale + shift;
        if (residual) o += residual[(size_t)r * C + c];
        out[(size_t)r * C + c] = o;
    }
}

extern "C" void kernel_launch(void* const* d_in, const int* in_sizes, int n_in,
                              void* d_out, int out_size, void* d_ws, size_t ws_size,
                              hipStream_t stream) {
    (void)in_sizes; (void)n_in; (void)out_size; (void)ws_size;
    const float* x      = (const float*)d_in[0];
    const int*   ei     = (const int*)d_in[1];   // [2, NE]
    const int*   batch  = (const int*)d_in[2];
    const int*   fei    = (const int*)d_in[3];   // [2, NFE]
    const float* W_gcn  = (const float*)d_in[4];  const float* b_gcn  = (const float*)d_in[5];
    const float* W_gcnx = (const float*)d_in[6];  const float* b_gcnx = (const float*)d_in[7];
    const float* W_gcny = (const float*)d_in[8];  const float* b_gcny = (const float*)d_in[9];
    const float* W_g1   = (const float*)d_in[10]; const float* b_g1   = (const float*)d_in[11];
    const float* W_g2   = (const float*)d_in[12]; const float* b_g2   = (const float*)d_in[13];
    const float* W_g3   = (const float*)d_in[14]; const float* b_g3   = (const float*)d_in[15];
    const float* gamma0 = (const float*)d_in[16]; const float* beta0  = (const float*)d_in[17];
    const float* gamma1 = (const float*)d_in[18]; const float* beta1  = (const float*)d_in[19];
    const float* gamma2 = (const float*)d_in[20]; const float* beta2  = (const float*)d_in[21];
    const float* gamma3 = (const float*)d_in[22]; const float* beta3  = (const float*)d_in[23];
    const float* Wc1    = (const float*)d_in[24]; const float* bc1    = (const float*)d_in[25];
    const float* Wc2    = (const float*)d_in[26]; const float* bc2    = (const float*)d_in[27];
    float* outp = (float*)d_out;

    char* ws = (char*)d_ws;
    size_t off = 0;
    auto alloc = [&](size_t bytes) -> char* {
        char* p = ws + off;
        off = (off + bytes + 255) & ~(size_t)255;
        return p;
    };

    int*   counts_f = (int*)alloc((size_t)NN * 4);
    int*   off_f    = (int*)alloc((size_t)(NN + 1) * 4);
    int*   cur_f    = (int*)alloc((size_t)(NN + 1) * 4);
    int*   csrc_f   = (int*)alloc((size_t)NE * 4);
    float* csw_f    = (float*)alloc((size_t)NE * 4);
    float* dinv_f   = (float*)alloc((size_t)NN * 4);

    int*   counts_g = (int*)alloc((size_t)NG * 4);
    int*   off_g    = (int*)alloc((size_t)(NG + 1) * 4);
    int*   cur_g    = (int*)alloc((size_t)(NG + 1) * 4);
    int*   csrc_g   = (int*)alloc((size_t)NFE * 4);
    float* csw_g    = (float*)alloc((size_t)NFE * 4);
    float* dinv_g   = (float*)alloc((size_t)NG * 4);

    int*   gcnt = (int*)alloc((size_t)NG * 4);
    int*   goff = (int*)alloc((size_t)(NG + 1) * 4);
    int*   part = (int*)alloc(1024 * 4);

    float*  bufA   = (float*)alloc((size_t)NN * 156 * 4);
    float*  bufB   = (float*)alloc((size_t)NN * 184 * 4);
    __half* hbuf   = (__half*)alloc((size_t)NN * 184 * 2);
    float*  pooled = (float*)alloc((size_t)NG * 184 * 4);
    float*  xn1    = (float*)alloc((size_t)NG * 128 * 4);
    float*  xn2    = (float*)alloc((size_t)NG * 156 * 4);
    float*  xn3    = (float*)alloc((size_t)NG * 184 * 4);
    float*  ctA    = (float*)alloc((size_t)NG * 212 * 4);
    float*  ctB    = (float*)alloc((size_t)NG * 212 * 4);

    auto cdiv = [](int a, int b) { return (a + b - 1) / b; };

    hipMemsetAsync(counts_f, 0, (size_t)NN * 4, stream);
    hipMemsetAsync(counts_g, 0, (size_t)NG * 4, stream);
    hipMemsetAsync(gcnt,     0, (size_t)NG * 4, stream);

    // ---- fine graph CSR ----
    k_count<<<cdiv(NE, 256), 256, 0, stream>>>(ei + NE, counts_f, NE);
    k_dinv<<<cdiv(NN, 256), 256, 0, stream>>>(counts_f, dinv_f, NN);
    int nbN = cdiv(NN, SCAN_CHUNK);
    k_scan_partial<<<nbN, SCAN_T, 0, stream>>>(counts_f, part, NN);
    k_scan_small<<<1, SCAN_T, 0, stream>>>(part, nbN);
    k_scan_apply<<<nbN, SCAN_T, 0, stream>>>(counts_f, part, off_f, cur_f, NN);
    k_fill<<<cdiv(NE, 256), 256, 0, stream>>>(ei, ei + NE, dinv_f, cur_f, csrc_f, csw_f, NE);

    // ---- full (coarse) graph CSR ----
    k_count<<<cdiv(NFE, 256), 256, 0, stream>>>(fei + NFE, counts_g, NFE);
    k_dinv<<<cdiv(NG, 256), 256, 0, stream>>>(counts_g, dinv_g, NG);
    int nbG = cdiv(NG, SCAN_CHUNK);
    k_scan_partial<<<nbG, SCAN_T, 0, stream>>>(counts_g, part, NG);
    k_scan_small<<<1, SCAN_T, 0, stream>>>(part, nbG);
    k_scan_apply<<<nbG, SCAN_T, 0, stream>>>(counts_g, part, off_g, cur_g, NG);
    k_fill<<<cdiv(NFE, 256), 256, 0, stream>>>(fei, fei + NFE, dinv_g, cur_g, csrc_g, csw_g, NFE);

    // ---- pooling offsets from sorted batch ----
    k_count<<<cdiv(NN, 256), 256, 0, stream>>>(batch, gcnt, NN);
    k_scan_partial<<<nbG, SCAN_T, 0, stream>>>(gcnt, part, NG);
    k_scan_small<<<1, SCAN_T, 0, stream>>>(part, nbG);
    k_scan_apply<<<nbG, SCAN_T, 0, stream>>>(gcnt, part, goff, nullptr, NG);

    // ==== fine branch ====
    // layer 1: t = x @ W_gcn^T (200->128), then h1 = relu(prop(t) + b_gcn)
    k_gemm_big<200><<<dim3(cdiv(NN, GBM), cdiv(128, GBN)), 256, 0, stream>>>(x, W_gcn, nullptr, bufA, NN, 128, 0);
    k_cvt<<<cdiv(NN * 128 / 4, 256), 256, 0, stream>>>(bufA, hbuf, (size_t)NN * 128 / 4);
    k_prop_t<128, true><<<cdiv(NN, 4), 256, 0, stream>>>(bufA, hbuf, off_f, csrc_f, csw_f, dinv_f, b_gcn, bufB, NN, 1);
    k_pool<<<NG, 256, 0, stream>>>(bufB, goff, pooled, 128);
    k_bn<<<128, 256, 0, stream>>>(pooled, gamma0, beta0, nullptr, xn1, NG, 128);

    // layer 2: h2 = relu(prop(h1) @ W_gcnx^T + b) (128->156)
    k_cvt<<<cdiv(NN * 128 / 4, 256), 256, 0, stream>>>(bufB, hbuf, (size_t)NN * 128 / 4);
    k_prop_t<128, true><<<cdiv(NN, 4), 256, 0, stream>>>(bufB, hbuf, off_f, csrc_f, csw_f, dinv_f, nullptr, bufA, NN, 0);
    k_gemm_big<128><<<dim3(cdiv(NN, GBM), cdiv(156, GBN)), 256, 0, stream>>>(bufA, W_gcnx, b_gcnx, bufB, NN, 156, 1);
    k_pool<<<NG, 256, 0, stream>>>(bufB, goff, pooled, 156);
    k_bn<<<156, 256, 0, stream>>>(pooled, gamma1, beta1, nullptr, xn2, NG, 156);

    // layer 3: h3 = relu(prop(h2) @ W_gcny^T + b) (156->184)
    k_cvt<<<cdiv(NN * 156 / 4, 256), 256, 0, stream>>>(bufB, hbuf, (size_t)NN * 156 / 4);
    k_prop_t<156, true><<<cdiv(NN, 4), 256, 0, stream>>>(bufB, hbuf, off_f, csrc_f, csw_f, dinv_f, nullptr, bufA, NN, 0);
    k_gemm_big<156><<<dim3(cdiv(NN, GBM), cdiv(184, GBN)), 256, 0, stream>>>(bufA, W_gcny, b_gcny, bufB, NN, 184, 1);
    k_pool<<<NG, 256, 0, stream>>>(bufB, goff, pooled, 184);
    k_bn<<<184, 256, 0, stream>>>(pooled, gamma2, beta2, nullptr, xn3, NG, 184);

    // ==== coarse chain (K=2 props, fp32 path) ====
    // g1: h = bn(relu(prop^2(xn1) @ Wg1^T + b)) + xn2
    k_prop_t<128, false><<<cdiv(NG, 4), 256, 0, stream>>>(xn1, nullptr, off_g, csrc_g, csw_g, dinv_g, nullptr, ctA, NG, 0);
    k_prop_t<128, false><<<cdiv(NG, 4), 256, 0, stream>>>(ctA, nullptr, off_g, csrc_g, csw_g, dinv_g, nullptr, ctB, NG, 0);
    k_gemm<<<dim3(cdiv(NG, BM), cdiv(156, BN)), 256, 0, stream>>>(ctB, W_g1, b_g1, ctA, NG, 128, 156, 1);
    k_bn<<<156, 256, 0, stream>>>(ctA, gamma1, beta1, xn2, ctB, NG, 156);
    // g2
    k_prop_t<156, false><<<cdiv(NG, 4), 256, 0, stream>>>(ctB, nullptr, off_g, csrc_g, csw_g, dinv_g, nullptr, ctA, NG, 0);
    k_prop_t<156, false><<<cdiv(NG, 4), 256, 0, stream>>>(ctA, nullptr, off_g, csrc_g, csw_g, dinv_g, nullptr, ctB, NG, 0);
    k_gemm<<<dim3(cdiv(NG, BM), cdiv(184, BN)), 256, 0, stream>>>(ctB, W_g2, b_g2, ctA, NG, 156, 184, 1);
    k_bn<<<184, 256, 0, stream>>>(ctA, gamma2, beta2, xn3, ctB, NG, 184);
    // g3
    k_prop_t<184, false><<<cdiv(NG, 4), 256, 0, stream>>>(ctB, nullptr, off_g, csrc_g, csw_g, dinv_g, nullptr, ctA, NG, 0);
    k_prop_t<184, false><<<cdiv(NG, 4), 256, 0, stream>>>(ctA, nullptr, off_g, csrc_g, csw_g, dinv_g, nullptr, ctB, NG, 0);
    k_gemm<<<dim3(cdiv(NG, BM), cdiv(212, BN)), 256, 0, stream>>>(ctB, W_g3, b_g3, ctA, NG, 184, 212, 1);
    k_bn<<<212, 256, 0, stream>>>(ctA, gamma3, beta3, nullptr, ctB, NG, 212);

    // ==== classifier ====
    k_gemm<<<dim3(cdiv(NG, BM), cdiv(106, BN)), 256, 0, stream>>>(ctB, Wc1, bc1, ctA, NG, 212, 106, 1);
    k_gemm<<<dim3(cdiv(NG, BM), cdiv(16, BN)), 256, 0, stream>>>(ctA, Wc2, bc2, outp, NG, 106, 16, 0);
}